// Round 4
// baseline (596.185 us; speedup 1.0000x reference)
//
#include <hip/hip_runtime.h>
#include <hip/hip_fp16.h>
#include <stdint.h>

#define NTOK 16384
#define HID 4096
#define NE 64
#define NQKV 192          // 3*NE
#define NCHUNK (HID / 64) // 64 K-chunks of BK=64

typedef _Float16 half8_t __attribute__((ext_vector_type(8)));
typedef float f32x4 __attribute__((ext_vector_type(4)));

#if __has_builtin(__builtin_amdgcn_exp2f)
#define EXP2F(x) __builtin_amdgcn_exp2f(x)
#else
#define EXP2F(x) exp2f(x)
#endif

// ---------------- W fp32 -> fp16 (RTN) + fragment-friendly reorder ----------------
// W16r[(k>>3)*1536 + col*8 + (k&7)]  (elements; 1536 = 192 cols * 8)
// so the 12 col-fragments for a given (k-block, q) sit at 256B-strided imm offsets.
__global__ void wconvert_kernel(const float* __restrict__ W, _Float16* __restrict__ W16r) {
    int t = blockIdx.x * blockDim.x + threadIdx.x;   // 98304 threads
    int col = t % NQKV;
    int g   = t / NQKV;                               // k-group of 8
    const float* src = W + (size_t)col * HID + g * 8;
    f32x4 a = *(const f32x4*)src;
    f32x4 b = *(const f32x4*)(src + 4);
    half8_t h;
    h[0] = (_Float16)a[0]; h[1] = (_Float16)a[1]; h[2] = (_Float16)a[2]; h[3] = (_Float16)a[3];
    h[4] = (_Float16)b[0]; h[5] = (_Float16)b[1]; h[6] = (_Float16)b[2]; h[7] = (_Float16)b[3];
    *(half8_t*)(W16r + (size_t)t * 8) = h;            // fully coalesced write
}

// ---------------- barrier-free register GEMM: mix = X @ W^T (fp16 MFMA) ----------------
// 1 wave per block, 512 blocks. Wave owns rows [32b, 32b+32) x all 192 cols.
// A-fragments loaded lane-direct from X (fp32->fp16 in reg), 1 chunk prefetch ahead.
// No LDS, no __syncthreads in the K-loop.
__global__ __launch_bounds__(64) void gemm_kernel(const float* __restrict__ X,
                                                  const _Float16* __restrict__ W16r,
                                                  float* __restrict__ mix) {
    const int lane = threadIdx.x;
    const int r0 = blockIdx.x * 32;
    const int q  = lane >> 4;        // 0..3  -> k-subgroup of 8
    const int rr = lane & 15;        // row-in-tile / col-in-tile

    f32x4 acc[2][12] = {};
    f32x4 raw[2][2][2];              // [row-tile][kk][2x f32x4] current chunk, fp32

    const float* aptr0 = X + (size_t)(r0 + rr) * HID + q * 8;
    const float* aptr1 = X + (size_t)(r0 + 16 + rr) * HID + q * 8;

    // prologue: load chunk 0
    #pragma unroll
    for (int kk = 0; kk < 2; ++kk) {
        raw[0][kk][0] = *(const f32x4*)(aptr0 + kk * 32);
        raw[0][kk][1] = *(const f32x4*)(aptr0 + kk * 32 + 4);
        raw[1][kk][0] = *(const f32x4*)(aptr1 + kk * 32);
        raw[1][kk][1] = *(const f32x4*)(aptr1 + kk * 32 + 4);
    }

    for (int kc = 0; kc < NCHUNK; ++kc) {
        // convert current chunk to fp16 fragments (frees raw for prefetch)
        half8_t a[2][2];
        #pragma unroll
        for (int rt = 0; rt < 2; ++rt)
            #pragma unroll
            for (int kk = 0; kk < 2; ++kk)
                #pragma unroll
                for (int u = 0; u < 4; ++u) {
                    a[rt][kk][u]     = (_Float16)raw[rt][kk][0][u];
                    a[rt][kk][u + 4] = (_Float16)raw[rt][kk][1][u];
                }
        // prefetch next chunk (WAR on raw; in flight across the MFMA phase)
        if (kc + 1 < NCHUNK) {
            const int o = (kc + 1) * 64;
            #pragma unroll
            for (int kk = 0; kk < 2; ++kk) {
                raw[0][kk][0] = *(const f32x4*)(aptr0 + o + kk * 32);
                raw[0][kk][1] = *(const f32x4*)(aptr0 + o + kk * 32 + 4);
                raw[1][kk][0] = *(const f32x4*)(aptr1 + o + kk * 32);
                raw[1][kk][1] = *(const f32x4*)(aptr1 + o + kk * 32 + 4);
            }
        }
        // B fragments from L2 (reordered layout -> one base + imm offsets) + MFMA
        #pragma unroll
        for (int kk = 0; kk < 2; ++kk) {
            const _Float16* bb = W16r + ((size_t)(kc * 2 + kk) * 4 + q) * 1536 + rr * 8;
            half8_t b[12];
            #pragma unroll
            for (int j = 0; j < 12; ++j)
                b[j] = *(const half8_t*)(bb + j * 128);   // +256B per col-tile
            #pragma unroll
            for (int j = 0; j < 12; ++j) {
                acc[0][j] = __builtin_amdgcn_mfma_f32_16x16x32_f16(a[0][kk], b[j], acc[0][j], 0, 0, 0);
                acc[1][j] = __builtin_amdgcn_mfma_f32_16x16x32_f16(a[1][kk], b[j], acc[1][j], 0, 0, 0);
            }
        }
    }

    // epilogue: C frag col=rr, row=q*4+rg
    #pragma unroll
    for (int rt = 0; rt < 2; ++rt)
        #pragma unroll
        for (int j = 0; j < 12; ++j)
            #pragma unroll
            for (int rg = 0; rg < 4; ++rg)
                mix[(size_t)(r0 + rt * 16 + q * 4 + rg) * NQKV + j * 16 + rr] = acc[rt][j][rg];
}

// ---------------- per-token outer-product softmax attention ----------------
// Block: 256 thr, 32 tokens. Stage mix[32][192] -> LDS, then separable-max softmax.
__global__ __launch_bounds__(256) void attn_kernel(const float* __restrict__ mix,
                                                   float* __restrict__ out) {
    __shared__ __align__(16) float mixS[32 * 200];   // stride 200 (800B, 16B-mult)

    const int tid  = threadIdx.x;
    const int lane = tid & 63;
    const int wid  = tid >> 6;
    const int tok0 = blockIdx.x * 32;

    // stage: 1536 f32x4 slots, 6 per thread
    #pragma unroll
    for (int p = 0; p < 6; ++p) {
        int s = tid + p * 256;
        int r = s / 48, g = s % 48;
        f32x4 v = *(const f32x4*)(mix + (size_t)(tok0 + r) * NQKV + g * 4);
        *(f32x4*)&mixS[r * 200 + g * 4] = v;
    }
    __syncthreads();

    const float L2E = 1.44269504088896f;
    for (int tt = 0; tt < 8; ++tt) {
        const int row = wid * 8 + tt;
        float q  = mixS[row * 200 + lane];
        float kl = mixS[row * 200 + NE + lane];
        float kmax = kl, kmin = kl;
        #pragma unroll
        for (int off = 32; off >= 1; off >>= 1) {
            kmax = fmaxf(kmax, __shfl_xor(kmax, off));
            kmin = fminf(kmin, __shfl_xor(kmin, off));
        }
        float m   = (q >= 0.0f) ? q * kmax : q * kmin;  // exact rowmax (separable)
        float ql  = q * L2E;
        float nml = -m * L2E;
        float sum = 0.0f, av = 0.0f;
        #pragma unroll 4
        for (int f4 = 0; f4 < 16; ++f4) {
            f32x4 kf = *(f32x4*)&mixS[row * 200 + NE + f4 * 4];     // uniform -> broadcast
            f32x4 vf = *(f32x4*)&mixS[row * 200 + 2 * NE + f4 * 4];
            #pragma unroll
            for (int u = 0; u < 4; ++u) {
                float p = EXP2F(fmaf(ql, kf[u], nml));
                sum += p;
                av = fmaf(p, vf[u], av);
            }
        }
        out[(size_t)(tok0 + row) * NE + lane] = av / sum;
    }
}

extern "C" void kernel_launch(void* const* d_in, const int* in_sizes, int n_in,
                              void* d_out, int out_size, void* d_ws, size_t ws_size,
                              hipStream_t stream) {
    const float* X = (const float*)d_in[0];   // [16384, 4096] fp32
    const float* W = (const float*)d_in[1];   // [192, 4096] fp32
    float* out = (float*)d_out;               // [16384, 64] fp32

    _Float16* W16r = (_Float16*)d_ws;                          // 1.5 MB
    float* mix = (float*)((char*)d_ws + (16u << 20));          // 12.6 MB at +16 MB

    wconvert_kernel<<<(NQKV * HID / 8) / 256, 256, 0, stream>>>(W, W16r);
    gemm_kernel<<<NTOK / 32, 64, 0, stream>>>(X, W16r, mix);
    attn_kernel<<<NTOK / 32, 256, 0, stream>>>(mix, out);
}